// Round 11
// baseline (308.609 us; speedup 1.0000x reference)
//
#include <hip/hip_runtime.h>
#include <hip/hip_bf16.h>
#include <stdint.h>
#include <stddef.h>

#define DEV static __device__ __forceinline__

typedef __attribute__((ext_vector_type(8))) short short8;   // 8 bf16 (4 VGPRs) MFMA A/B frag
typedef __attribute__((ext_vector_type(4))) float floatx4;  // MFMA C/D frag

constexpr int Tn = 4096, Dn = 512;
constexpr int NC = 128, CTm = 32;   // scan: 128 chunks of 32 along T

union U8s { uint4 u4; unsigned short us[8]; };
union U4f { float4 f4; float f[4]; };
union U4s { uint2 u2; unsigned short us[4]; };

DEV float b2f(unsigned short u) {
  union { unsigned int i; float f; } c; c.i = ((unsigned int)u) << 16; return c.f;
}
DEV unsigned short f2b(float f) {  // RNE float->bf16
  union { float f; unsigned int u; } c; c.f = f;
  unsigned int r = c.u + 0x7fffu + ((c.u >> 16) & 1u);
  return (unsigned short)(r >> 16);
}
DEV float fast_tanh(float x) {     // robust at +/-inf: 1-2/(e^{2x}+1)
  float e = __expf(2.0f * x);
  return 1.0f - 2.0f / (e + 1.0f);
}

typedef __attribute__((address_space(1))) void GVOID;
typedef __attribute__((address_space(3))) void LVOID;
DEV void async16(const unsigned short* g, unsigned short* l) {
  __builtin_amdgcn_global_load_lds((GVOID*)g, (LVOID*)l, 16, 0, 0);
}

// ===== dispatch 1: scan pass 1 + weight prep + s1 = summ@W1 (fp32) ==========
// grid 680 x 256: [0,512) scan_partial ; [512,640) transposes Wh/Wo ;
//                 [640,672) W2 convert ; [672,680) s1 blocks (64 cols each)
__global__ void k_fuse1(const float* __restrict__ dec, float* __restrict__ part,
                        const float* __restrict__ Wh, const float* __restrict__ Wo,
                        const float* __restrict__ W2, const float* __restrict__ W1,
                        const float* __restrict__ summ,
                        unsigned short* __restrict__ WhT, unsigned short* __restrict__ WoT,
                        unsigned short* __restrict__ W2b, float* __restrict__ s1) {
  __shared__ float t[64][65];     // transpose tile; reused as reduce buf by s1
  int blk = blockIdx.x;
  int tid = threadIdx.x;
  if (blk < 512) {          // ---- scan pass 1: per-chunk partial sums (fp32)
    int idx = blk * 256 + tid;   // B*NC*(D/4) = 131072 threads
    int d4 = idx & 127;
    int c  = (idx >> 7) & (NC - 1);
    int b  = idx >> 14;
    const float* p = dec + ((size_t)b * Tn + (size_t)c * CTm) * Dn + d4 * 4;
    float s[4] = {0,0,0,0};
#pragma unroll 4
    for (int i = 0; i < CTm; ++i) {
      U4f v; v.f4 = *(const float4*)(p + (size_t)i * Dn);
#pragma unroll
      for (int j = 0; j < 4; ++j) s[j] += v.f[j];
    }
    float* o = part + ((size_t)(b * NC + c)) * Dn + d4 * 4;
#pragma unroll
    for (int j = 0; j < 4; ++j) o[j] = s[j];
  } else if (blk < 640) {   // ---- transpose: Wh->WhT, Wo->WoT
    int wb = blk - 512;
    const float* in = (wb < 64) ? Wh : Wo;
    unsigned short* out = (wb < 64) ? WhT : WoT;
    int lb = wb & 63;
    int n0 = (lb & 7) * 64, k0 = (lb >> 3) * 64;
#pragma unroll
    for (int l = 0; l < 16; ++l) {
      int lin = l * 256 + tid;
      int r = lin >> 6, c = lin & 63;
      t[r][c] = in[(size_t)(k0 + r) * 512 + n0 + c];
    }
    __syncthreads();
#pragma unroll
    for (int l = 0; l < 16; ++l) {
      int lin = l * 256 + tid;
      int r = lin >> 6, c = lin & 63;
      out[(size_t)(n0 + r) * 512 + k0 + c] = f2b(t[c][r]);
    }
  } else if (blk < 672) {   // ---- convert W2 -> W2b (bf16)
    int lb = (blk - 640) & 31;
    size_t base = ((size_t)lb * 256 + tid) * 32;
#pragma unroll
    for (int l = 0; l < 8; ++l) {
      U4f v; v.f4 = *(const float4*)(W2 + base + l * 4);
      U4s o;
#pragma unroll
      for (int j = 0; j < 4; ++j) o.us[j] = f2b(v.f[j]);
      *(uint2*)(W2b + base + l * 4) = o.u2;
    }
  } else {                  // ---- s1[b][n] = sum_j summ[b][j]*W1[j][n]
    int bb = blk - 672;                   // n in [bb*64, bb*64+64)
    int tn = tid & 63, tj = tid >> 6;     // 4 stripes of 128 j
    float a[8] = {0,0,0,0,0,0,0,0};
    for (int j = tj * 128; j < tj * 128 + 128; ++j) {
      float wv = W1[(size_t)j * 512 + bb * 64 + tn];   // coalesced
#pragma unroll
      for (int b = 0; b < 8; ++b) a[b] += summ[b * 512 + j] * wv;
    }
    float* red = &t[0][0];                // reuse transpose LDS (>= 2048 floats)
#pragma unroll
    for (int b = 0; b < 8; ++b) red[tj * 512 + b * 64 + tn] = a[b];
    __syncthreads();
    if (tj == 0) {
#pragma unroll
      for (int b = 0; b < 8; ++b)
        s1[b * 512 + bb * 64 + tn] = red[b * 64 + tn] + red[512 + b * 64 + tn] +
                                     red[1024 + b * 64 + tn] + red[1536 + b * 64 + tn];
    }
  }
}

// ===== 64-row full-width core (weight GEMM only): C = bf16(acc) =============
DEV void gemm64_core(const unsigned short* __restrict__ A,
                     const unsigned short* __restrict__ BT,
                     unsigned short* __restrict__ C, int m0) {
  __shared__ alignas(16) unsigned short sA[64 * 32];    // 4 KB
  __shared__ alignas(16) unsigned short sB[512 * 32];   // 32 KB
  const int tid  = threadIdx.x;
  const int lane = tid & 63;
  const int w    = tid >> 6;
  const int wr   = w >> 2;
  const int wc   = w & 3;
  const int rs   = lane & 15;
  const int quad = lane >> 4;

  floatx4 acc[2][8];
#pragma unroll
  for (int i = 0; i < 2; ++i)
#pragma unroll
    for (int j = 0; j < 8; ++j) acc[i][j] = (floatx4){0.f, 0.f, 0.f, 0.f};

  for (int t = 0; t < 16; ++t) {
    const int kt = t * 32;
    if (tid < 256) {
      int r = tid >> 2, c = tid & 3;
      int kc = (c ^ ((r >> 1) & 3)) * 8;
      async16(A + (size_t)(m0 + r) * 512 + kt + kc, &sA[tid * 8]);
    }
#pragma unroll
    for (int l = 0; l < 4; ++l) {
      int ch = l * 512 + tid;
      int r = ch >> 2, c = ch & 3;
      int kc = (c ^ ((r >> 1) & 3)) * 8;
      async16(BT + (size_t)r * 512 + kt + kc, &sB[ch * 8]);
    }
    asm volatile("s_waitcnt vmcnt(0)" ::: "memory");
    __syncthreads();

    const int co = (quad ^ ((rs >> 1) & 3)) * 8;
    short8 af0 = *(const short8*)(&sA[(wr * 32 + rs) * 32 + co]);
    short8 af1 = *(const short8*)(&sA[(wr * 32 + 16 + rs) * 32 + co]);
#pragma unroll
    for (int nj = 0; nj < 8; ++nj) {
      short8 bf = *(const short8*)(&sB[(wc * 128 + nj * 16 + rs) * 32 + co]);
      acc[0][nj] = __builtin_amdgcn_mfma_f32_16x16x32_bf16(af0, bf, acc[0][nj], 0, 0, 0);
      acc[1][nj] = __builtin_amdgcn_mfma_f32_16x16x32_bf16(af1, bf, acc[1][nj], 0, 0, 0);
    }
    __syncthreads();
  }

#pragma unroll
  for (int nj = 0; nj < 8; ++nj) {
    const int colg = wc * 128 + nj * 16 + rs;
#pragma unroll
    for (int mi = 0; mi < 2; ++mi) {
#pragma unroll
      for (int r = 0; r < 4; ++r) {
        const int rowg = m0 + wr * 32 + mi * 16 + quad * 4 + r;
        C[(size_t)rowg * 512 + colg] = f2b(acc[mi][nj][r]);
      }
    }
  }
}

// ===== dispatch 2: W2@Wo GEMM + spo finish + scan_apply (inline prefix) =====
// grid 272 x 512: [0,8) W2Wo m-tiles ; [8,16) spo = s1@Wo + bo ;
//                 [16,272) scan_apply with inline exclusive chunk-prefix
__global__ __launch_bounds__(512, 2)
void k_fuse2(const unsigned short* __restrict__ WoT, const unsigned short* __restrict__ W2b,
             unsigned short* __restrict__ W2WoT,
             const float* __restrict__ s1, const float* __restrict__ Wo,
             const float* __restrict__ bo, float* __restrict__ spo,
             const float* __restrict__ dec, const float* __restrict__ part,
             unsigned short* __restrict__ M) {
  __shared__ float red[8][8][64];   // spo reduce (16 KB)
  int blk = blockIdx.x;
  int tid = threadIdx.x;
  if (blk < 8) {            // ---- W2WoT = (W2@Wo)^T tile
    gemm64_core(WoT, W2b, W2WoT, blk * 64);
  } else if (blk < 16) {    // ---- spo[b][n] = bo[n] + sum_j s1[b][j]*Wo[j][n]
    int bb = blk - 8;                     // n in [bb*64, bb*64+64)
    int tn = tid & 63, tj = tid >> 6;     // 8 stripes of 64 j
    float a[8] = {0,0,0,0,0,0,0,0};
    for (int j = tj * 64; j < tj * 64 + 64; ++j) {
      float wv = Wo[(size_t)j * 512 + bb * 64 + tn];   // coalesced
#pragma unroll
      for (int b = 0; b < 8; ++b) a[b] += s1[b * 512 + j] * wv;
    }
#pragma unroll
    for (int b = 0; b < 8; ++b) red[tj][b][tn] = a[b];
    __syncthreads();
    if (tj == 0) {
#pragma unroll
      for (int b = 0; b < 8; ++b) {
        float s = 0.f;
#pragma unroll
        for (int k = 0; k < 8; ++k) s += red[k][b][tn];
        spo[b * 512 + bb * 64 + tn] = s + bo[bb * 64 + tn];
      }
    }
  } else {                  // ---- scan_apply: running mean -> bf16 M
    int idx = (blk - 16) * 512 + tid;   // B*NC*(D/4) = 131072 threads
    int d4 = idx & 127;
    int c  = (idx >> 7) & (NC - 1);
    int b  = idx >> 14;
    size_t rbase = (size_t)b * Tn + (size_t)c * CTm;
    // inline EXCLUSIVE prefix over preceding chunk sums (L2/L3-resident part)
    const float* pb = part + (size_t)b * NC * Dn + d4 * 4;
    float s[4] = {0, 0, 0, 0};
    int cc = 0;
    for (; cc + 8 <= c; cc += 8) {        // 8 loads in flight
      U4f v[8];
#pragma unroll
      for (int i = 0; i < 8; ++i) v[i].f4 = *(const float4*)(pb + (size_t)(cc + i) * Dn);
#pragma unroll
      for (int i = 0; i < 8; ++i)
#pragma unroll
        for (int j = 0; j < 4; ++j) s[j] += v[i].f[j];
    }
    for (; cc < c; ++cc) {
      U4f v; v.f4 = *(const float4*)(pb + (size_t)cc * Dn);
#pragma unroll
      for (int j = 0; j < 4; ++j) s[j] += v.f[j];
    }
    int t0 = c * CTm;
    const float* dp = dec + rbase * Dn + d4 * 4;
    unsigned short* mp = M + rbase * Dn + d4 * 4;
#pragma unroll 4
    for (int i = 0; i < CTm; ++i) {
      U4f v; v.f4 = *(const float4*)(dp + (size_t)i * Dn);
      float inv = 1.0f / (float)(t0 + i + 1);
      U4s o;
#pragma unroll
      for (int j = 0; j < 4; ++j) { s[j] += v.f[j]; o.us[j] = f2b(s[j] * inv); }
      *(uint2*)(mp + (size_t)i * Dn) = o.u2;
    }
  }
}

// ===== dispatch 3: fused H-GEMM -> (regs->LDS) -> F-GEMM -> residual+LN =====
// 256 blocks x 1024 thr (16 waves: 4 M-bands x 4 N-bands), 1 block/CU.
// Phase 1: acc1 = M@Wh (R8 counted-vmcnt K-loop).  H = tanh(acc1+bh) never
// touches HBM: per phase-2 K-chunk kk, the 4 waves with wc==kk>>2 ds_write
// their bf16 slice into sH (dbuf, sA-layout+swizzle), lgkmcnt(0)+barrier, and
// all waves ds_read it as the MFMA A-operand.  Phase 2: acc2 = H@W2WoT with
// B staged from L2 (counted vmcnt(2)).  Epilogue: fused residual+LayerNorm.
// launch_bounds(1024,4): 4 waves/EU = 1 block/CU -> VGPR cap 512 so
// acc1+acc2 (256 regs) stay in the unified file.  Phase-2 loop is FULLY
// UNROLLED so WRITEH's acc1[mi][(kk&3)*2+q] index is compile-time (rule #20:
// runtime-indexed ext_vector arrays spill to scratch -- R10's 156us, 212MB
// WRITE_SIZE regression).
__global__ __launch_bounds__(1024, 4)
void k_fused(const unsigned short* __restrict__ A,      // Mbuf
             const unsigned short* __restrict__ B1T,    // WhT
             const unsigned short* __restrict__ B2T,    // W2WoT
             const float* __restrict__ bh, const float* __restrict__ spo,
             const float* __restrict__ dec,
             const float* __restrict__ gamma, const float* __restrict__ beta,
             float* __restrict__ out) {
  __shared__ alignas(16) unsigned short sA[2][128 * 32];   // 16 KB
  __shared__ alignas(16) unsigned short sB[2][512 * 32];   // 64 KB
  __shared__ alignas(16) unsigned short sH[2][128 * 32];   // 16 KB
  __shared__ float lnS[128][4];
  __shared__ float lnQ[128][4];
  const int m0   = blockIdx.x * 128;
  const int tid  = threadIdx.x;
  const int lane = tid & 63;
  const int w    = tid >> 6;        // 0..15
  const int wr   = w >> 2;          // 0..3  (32-row band)
  const int wc   = w & 3;           // 0..3  (128-col band)
  const int rs   = lane & 15;
  const int quad = lane >> 4;

  floatx4 acc1[2][8], acc2[2][8];
#pragma unroll
  for (int i = 0; i < 2; ++i)
#pragma unroll
    for (int j = 0; j < 8; ++j) {
      acc1[i][j] = (floatx4){0.f, 0.f, 0.f, 0.f};
      acc2[i][j] = (floatx4){0.f, 0.f, 0.f, 0.f};
    }

  const int co = (quad ^ ((rs >> 1) & 3)) * 8;   // swizzled read chunk (elems)

  auto STAGE1 = [&](int kt, int buf) {
    if (tid < 512) {
      int r = tid >> 2, c = tid & 3;
      int kc = (c ^ ((r >> 1) & 3)) * 8;
      async16(A + (size_t)(m0 + r) * 512 + kt + kc, &sA[buf][tid * 8]);
    }
#pragma unroll
    for (int l = 0; l < 2; ++l) {
      int ch = l * 1024 + tid;
      int r = ch >> 2, c = ch & 3;
      int kc = (c ^ ((r >> 1) & 3)) * 8;
      async16(B1T + (size_t)r * 512 + kt + kc, &sB[buf][ch * 8]);
    }
  };
  auto STAGE2 = [&](int kt, int buf) {
#pragma unroll
    for (int l = 0; l < 2; ++l) {
      int ch = l * 1024 + tid;
      int r = ch >> 2, c = ch & 3;
      int kc = (c ^ ((r >> 1) & 3)) * 8;
      async16(B2T + (size_t)r * 512 + kt + kc, &sB[buf][ch * 8]);
    }
  };
  auto COMPUTE1 = [&](int buf) {
    __builtin_amdgcn_s_setprio(1);
    short8 af0 = *(const short8*)(&sA[buf][(wr * 32 + rs) * 32 + co]);
    short8 af1 = *(const short8*)(&sA[buf][(wr * 32 + 16 + rs) * 32 + co]);
#pragma unroll
    for (int nj = 0; nj < 8; ++nj) {
      short8 bf = *(const short8*)(&sB[buf][(wc * 128 + nj * 16 + rs) * 32 + co]);
      acc1[0][nj] = __builtin_amdgcn_mfma_f32_16x16x32_bf16(af0, bf, acc1[0][nj], 0, 0, 0);
      acc1[1][nj] = __builtin_amdgcn_mfma_f32_16x16x32_bf16(af1, bf, acc1[1][nj], 0, 0, 0);
    }
    __builtin_amdgcn_s_setprio(0);
  };
  auto COMPUTE2 = [&](int buf) {
    __builtin_amdgcn_s_setprio(1);
    short8 af0 = *(const short8*)(&sH[buf][(wr * 32 + rs) * 32 + co]);
    short8 af1 = *(const short8*)(&sH[buf][(wr * 32 + 16 + rs) * 32 + co]);
#pragma unroll
    for (int nj = 0; nj < 8; ++nj) {
      short8 bf = *(const short8*)(&sB[buf][(wc * 128 + nj * 16 + rs) * 32 + co]);
      acc2[0][nj] = __builtin_amdgcn_mfma_f32_16x16x32_bf16(af0, bf, acc2[0][nj], 0, 0, 0);
      acc2[1][nj] = __builtin_amdgcn_mfma_f32_16x16x32_bf16(af1, bf, acc2[1][nj], 0, 0, 0);
    }
    __builtin_amdgcn_s_setprio(0);
  };

  // ---- phase 1: acc1 = M @ Wh ----
  STAGE1(0, 0);
  for (int t = 0; t < 15; ++t) {
    STAGE1((t + 1) * 32, (t + 1) & 1);
    if (w < 8) asm volatile("s_waitcnt vmcnt(3)\n\ts_barrier" ::: "memory");
    else       asm volatile("s_waitcnt vmcnt(2)\n\ts_barrier" ::: "memory");
    COMPUTE1(t & 1);
    asm volatile("s_barrier" ::: "memory");
  }
  asm volatile("s_waitcnt vmcnt(0)\n\ts_barrier" ::: "memory");
  COMPUTE1(1);

  // bias for this thread's 8 columns (loaded after phase-1 vmcnt drained)
  float bb[8];
#pragma unroll
  for (int nj = 0; nj < 8; ++nj) bb[nj] = bh[wc * 128 + nj * 16 + rs];

  // writers for chunk kk: waves with wc == kk>>2; 16 bf16 each, sA-layout+swz
  // kk must be a COMPILE-TIME constant at every call site (rule #20).
  auto WRITEH = [&](int kk, int buf) {
    if (wc == (kk >> 2)) {
      const int njb = (kk & 3) * 2;
#pragma unroll
      for (int q = 0; q < 2; ++q) {
        const int col = q * 16 + rs;                 // within-chunk k col 0..31
#pragma unroll
        for (int mi = 0; mi < 2; ++mi)
#pragma unroll
          for (int r = 0; r < 4; ++r) {
            const int row = wr * 32 + mi * 16 + quad * 4 + r;
            const int ch = (col >> 3) ^ ((row >> 1) & 3);
            sH[buf][row * 32 + ch * 8 + (col & 7)] =
                f2b(fast_tanh(acc1[mi][njb + q][r] + bb[njb + q]));
          }
      }
    }
  };

  // transition: all waves done with phase-1 reads of sB before phase-2 reuse
  asm volatile("s_barrier" ::: "memory");

  // ---- phase 2: acc2 = H @ W2WoT ---- (FULLY UNROLLED: static acc1 indices)
  WRITEH(0, 0);
  STAGE2(0, 0);
#pragma unroll
  for (int kk = 0; kk < 16; ++kk) {
    if (kk < 15) {
      WRITEH(kk + 1, (kk + 1) & 1);
      STAGE2((kk + 1) * 32, (kk + 1) & 1);
      asm volatile("s_waitcnt vmcnt(2) lgkmcnt(0)\n\ts_barrier" ::: "memory");
    } else {
      asm volatile("s_waitcnt vmcnt(0) lgkmcnt(0)\n\ts_barrier" ::: "memory");
    }
    COMPUTE2(kk & 1);
    asm volatile("s_barrier" ::: "memory");
  }

  // ---- epilogue: F = tanh(spo - acc2); x = F + dec; out = LN(x) ----
  const int bidx = m0 >> 12;              // batch (4096 rows each)
#pragma unroll
  for (int mi = 0; mi < 2; ++mi) {
#pragma unroll
    for (int r = 0; r < 4; ++r) {
      const int lrow = wr * 32 + mi * 16 + quad * 4 + r;
      const size_t rowg = (size_t)(m0 + lrow);
      float s = 0.f, sq = 0.f;
#pragma unroll
      for (int nj = 0; nj < 8; ++nj) {
        const int colg = wc * 128 + nj * 16 + rs;
        float sp = spo[bidx * Dn + colg];
        float dv = dec[rowg * 512 + colg];
        float xf = fast_tanh(sp - acc2[mi][nj][r]) + dv;
        acc2[mi][nj][r] = xf;
        s += xf; sq += xf * xf;
      }
#pragma unroll
      for (int o = 8; o > 0; o >>= 1) { s += __shfl_xor(s, o, 64); sq += __shfl_xor(sq, o, 64); }
      if (rs == 0) { lnS[lrow][wc] = s; lnQ[lrow][wc] = sq; }
    }
  }
  __syncthreads();
#pragma unroll
  for (int mi = 0; mi < 2; ++mi) {
#pragma unroll
    for (int r = 0; r < 4; ++r) {
      const int lrow = wr * 32 + mi * 16 + quad * 4 + r;
      const size_t rowg = (size_t)(m0 + lrow);
      float s = 0.f, sq = 0.f;
#pragma unroll
      for (int k = 0; k < 4; ++k) { s += lnS[lrow][k]; sq += lnQ[lrow][k]; }
      float mu   = s * (1.0f / 512.0f);
      float var  = sq * (1.0f / 512.0f) - mu * mu;
      float rstd = rsqrtf(var + 1e-6f);
#pragma unroll
      for (int nj = 0; nj < 8; ++nj) {
        const int colg = wc * 128 + nj * 16 + rs;
        out[rowg * 512 + colg] = (acc2[mi][nj][r] - mu) * rstd * gamma[colg] + beta[colg];
      }
    }
  }
}

extern "C" void kernel_launch(void* const* d_in, const int* in_sizes, int n_in,
                              void* d_out, int out_size, void* d_ws, size_t ws_size,
                              hipStream_t stream) {
  (void)in_sizes; (void)n_in; (void)out_size; (void)ws_size;
  const float* summ = (const float*)d_in[0];
  const float* dec  = (const float*)d_in[1];
  const float* Wh   = (const float*)d_in[2];
  const float* bh   = (const float*)d_in[3];
  const float* W1   = (const float*)d_in[4];
  const float* W2   = (const float*)d_in[5];
  const float* Wo   = (const float*)d_in[6];
  const float* bo   = (const float*)d_in[7];
  const float* gam  = (const float*)d_in[8];
  const float* bet  = (const float*)d_in[9];
  float* out = (float*)d_out;

  char* ws = (char*)d_ws;
  unsigned short* Mbuf  = (unsigned short*)(ws);                 // 32 MB bf16 M
  float*          part  = (float*)(ws + 67108864);               // 2 MB fp32 chunk sums
  float*          spo   = (float*)(ws + 69206016);               // 16 KB
  unsigned short* WhT   = (unsigned short*)(ws + 69238784);      // 512 KB bf16
  unsigned short* WoT   = (unsigned short*)(ws + 69763072);      // 512 KB bf16
  unsigned short* W2b   = (unsigned short*)(ws + 70287360);      // 512 KB bf16
  unsigned short* W2WoT = (unsigned short*)(ws + 70811648);      // 512 KB bf16 (= (W2@Wo)^T)
  float*          s1    = (float*)(ws + 71335936);               // 16 KB fp32 (summ@W1)

  // 1: chunk sums + weight transposes/convert + s1 = summ@W1
  k_fuse1<<<680, 256, 0, stream>>>(dec, part, Wh, Wo, W2, W1, summ, WhT, WoT, W2b, s1);

  // 2: W2@Wo GEMM + spo = s1@Wo + bo + causal running mean -> M (inline prefix)
  k_fuse2<<<272, 512, 0, stream>>>(WoT, W2b, W2WoT, s1, Wo, bo, spo, dec, part, Mbuf);

  // 3: fused  H = tanh(M@Wh+bh)  ->  out = LN(tanh(spo - H@W2Wo) + dec)
  k_fused<<<256, 1024, 0, stream>>>(Mbuf, WhT, W2WoT, bh, spo, dec, gam, bet, out);
}

// Round 12
// 255.920 us; speedup vs baseline: 1.2059x; 1.2059x over previous
//
#include <hip/hip_runtime.h>
#include <hip/hip_bf16.h>
#include <stdint.h>
#include <stddef.h>

#define DEV static __device__ __forceinline__

typedef __attribute__((ext_vector_type(8))) short short8;   // 8 bf16 (4 VGPRs) MFMA A/B frag
typedef __attribute__((ext_vector_type(4))) float floatx4;  // MFMA C/D frag

constexpr int Tn = 4096, Dn = 512;
constexpr int NC = 128, CTm = 32;   // scan: 128 chunks of 32 along T

union U8s { uint4 u4; unsigned short us[8]; };
union U4f { float4 f4; float f[4]; };
union U4s { uint2 u2; unsigned short us[4]; };

DEV float b2f(unsigned short u) {
  union { unsigned int i; float f; } c; c.i = ((unsigned int)u) << 16; return c.f;
}
DEV unsigned short f2b(float f) {  // RNE float->bf16
  union { float f; unsigned int u; } c; c.f = f;
  unsigned int r = c.u + 0x7fffu + ((c.u >> 16) & 1u);
  return (unsigned short)(r >> 16);
}
DEV float fast_tanh(float x) {     // robust at +/-inf: 1-2/(e^{2x}+1)
  float e = __expf(2.0f * x);
  return 1.0f - 2.0f / (e + 1.0f);
}

typedef __attribute__((address_space(1))) void GVOID;
typedef __attribute__((address_space(3))) void LVOID;
DEV void async16(const unsigned short* g, unsigned short* l) {
  __builtin_amdgcn_global_load_lds((GVOID*)g, (LVOID*)l, 16, 0, 0);
}

// ===== dispatch 1: scan pass 1 + weight prep + s1 = summ@W1 (fp32) ==========
// grid 680 x 256: [0,512) scan_partial ; [512,640) transposes Wh/Wo ;
//                 [640,672) W2 convert ; [672,680) s1 blocks (64 cols each)
__global__ void k_fuse1(const float* __restrict__ dec, float* __restrict__ part,
                        const float* __restrict__ Wh, const float* __restrict__ Wo,
                        const float* __restrict__ W2, const float* __restrict__ W1,
                        const float* __restrict__ summ,
                        unsigned short* __restrict__ WhT, unsigned short* __restrict__ WoT,
                        unsigned short* __restrict__ W2b, float* __restrict__ s1) {
  __shared__ float t[64][65];     // transpose tile; reused as reduce buf by s1
  int blk = blockIdx.x;
  int tid = threadIdx.x;
  if (blk < 512) {          // ---- scan pass 1: per-chunk partial sums (fp32)
    int idx = blk * 256 + tid;   // B*NC*(D/4) = 131072 threads
    int d4 = idx & 127;
    int c  = (idx >> 7) & (NC - 1);
    int b  = idx >> 14;
    const float* p = dec + ((size_t)b * Tn + (size_t)c * CTm) * Dn + d4 * 4;
    float s[4] = {0,0,0,0};
#pragma unroll 4
    for (int i = 0; i < CTm; ++i) {
      U4f v; v.f4 = *(const float4*)(p + (size_t)i * Dn);
#pragma unroll
      for (int j = 0; j < 4; ++j) s[j] += v.f[j];
    }
    float* o = part + ((size_t)(b * NC + c)) * Dn + d4 * 4;
#pragma unroll
    for (int j = 0; j < 4; ++j) o[j] = s[j];
  } else if (blk < 640) {   // ---- transpose: Wh->WhT, Wo->WoT
    int wb = blk - 512;
    const float* in = (wb < 64) ? Wh : Wo;
    unsigned short* out = (wb < 64) ? WhT : WoT;
    int lb = wb & 63;
    int n0 = (lb & 7) * 64, k0 = (lb >> 3) * 64;
#pragma unroll
    for (int l = 0; l < 16; ++l) {
      int lin = l * 256 + tid;
      int r = lin >> 6, c = lin & 63;
      t[r][c] = in[(size_t)(k0 + r) * 512 + n0 + c];
    }
    __syncthreads();
#pragma unroll
    for (int l = 0; l < 16; ++l) {
      int lin = l * 256 + tid;
      int r = lin >> 6, c = lin & 63;
      out[(size_t)(n0 + r) * 512 + k0 + c] = f2b(t[c][r]);
    }
  } else if (blk < 672) {   // ---- convert W2 -> W2b (bf16)
    int lb = (blk - 640) & 31;
    size_t base = ((size_t)lb * 256 + tid) * 32;
#pragma unroll
    for (int l = 0; l < 8; ++l) {
      U4f v; v.f4 = *(const float4*)(W2 + base + l * 4);
      U4s o;
#pragma unroll
      for (int j = 0; j < 4; ++j) o.us[j] = f2b(v.f[j]);
      *(uint2*)(W2b + base + l * 4) = o.u2;
    }
  } else {                  // ---- s1[b][n] = sum_j summ[b][j]*W1[j][n]
    int bb = blk - 672;                   // n in [bb*64, bb*64+64)
    int tn = tid & 63, tj = tid >> 6;     // 4 stripes of 128 j
    float a[8] = {0,0,0,0,0,0,0,0};
    for (int j = tj * 128; j < tj * 128 + 128; ++j) {
      float wv = W1[(size_t)j * 512 + bb * 64 + tn];   // coalesced
#pragma unroll
      for (int b = 0; b < 8; ++b) a[b] += summ[b * 512 + j] * wv;
    }
    float* red = &t[0][0];                // reuse transpose LDS (>= 2048 floats)
#pragma unroll
    for (int b = 0; b < 8; ++b) red[tj * 512 + b * 64 + tn] = a[b];
    __syncthreads();
    if (tj == 0) {
#pragma unroll
      for (int b = 0; b < 8; ++b)
        s1[b * 512 + bb * 64 + tn] = red[b * 64 + tn] + red[512 + b * 64 + tn] +
                                     red[1024 + b * 64 + tn] + red[1536 + b * 64 + tn];
    }
  }
}

// ===== 64-row full-width core (weight GEMM only): C = bf16(acc) =============
DEV void gemm64_core(const unsigned short* __restrict__ A,
                     const unsigned short* __restrict__ BT,
                     unsigned short* __restrict__ C, int m0) {
  __shared__ alignas(16) unsigned short sA[64 * 32];    // 4 KB
  __shared__ alignas(16) unsigned short sB[512 * 32];   // 32 KB
  const int tid  = threadIdx.x;
  const int lane = tid & 63;
  const int w    = tid >> 6;
  const int wr   = w >> 2;
  const int wc   = w & 3;
  const int rs   = lane & 15;
  const int quad = lane >> 4;

  floatx4 acc[2][8];
#pragma unroll
  for (int i = 0; i < 2; ++i)
#pragma unroll
    for (int j = 0; j < 8; ++j) acc[i][j] = (floatx4){0.f, 0.f, 0.f, 0.f};

  for (int t = 0; t < 16; ++t) {
    const int kt = t * 32;
    if (tid < 256) {
      int r = tid >> 2, c = tid & 3;
      int kc = (c ^ ((r >> 1) & 3)) * 8;
      async16(A + (size_t)(m0 + r) * 512 + kt + kc, &sA[tid * 8]);
    }
#pragma unroll
    for (int l = 0; l < 4; ++l) {
      int ch = l * 512 + tid;
      int r = ch >> 2, c = ch & 3;
      int kc = (c ^ ((r >> 1) & 3)) * 8;
      async16(BT + (size_t)r * 512 + kt + kc, &sB[ch * 8]);
    }
    asm volatile("s_waitcnt vmcnt(0)" ::: "memory");
    __syncthreads();

    const int co = (quad ^ ((rs >> 1) & 3)) * 8;
    short8 af0 = *(const short8*)(&sA[(wr * 32 + rs) * 32 + co]);
    short8 af1 = *(const short8*)(&sA[(wr * 32 + 16 + rs) * 32 + co]);
#pragma unroll
    for (int nj = 0; nj < 8; ++nj) {
      short8 bf = *(const short8*)(&sB[(wc * 128 + nj * 16 + rs) * 32 + co]);
      acc[0][nj] = __builtin_amdgcn_mfma_f32_16x16x32_bf16(af0, bf, acc[0][nj], 0, 0, 0);
      acc[1][nj] = __builtin_amdgcn_mfma_f32_16x16x32_bf16(af1, bf, acc[1][nj], 0, 0, 0);
    }
    __syncthreads();
  }

#pragma unroll
  for (int nj = 0; nj < 8; ++nj) {
    const int colg = wc * 128 + nj * 16 + rs;
#pragma unroll
    for (int mi = 0; mi < 2; ++mi) {
#pragma unroll
      for (int r = 0; r < 4; ++r) {
        const int rowg = m0 + wr * 32 + mi * 16 + quad * 4 + r;
        C[(size_t)rowg * 512 + colg] = f2b(acc[mi][nj][r]);
      }
    }
  }
}

// ===== dispatch 2: W2@Wo GEMM + spo finish + part exclusive-scan ============
// grid 18 x 512: [0,8) W2Wo m-tiles ; [8,16) spo = s1@Wo + bo ;
//                [16,18) in-place exclusive prefix over part (parallel)
__global__ __launch_bounds__(512, 2)
void k_fuse2(const unsigned short* __restrict__ WoT, const unsigned short* __restrict__ W2b,
             unsigned short* __restrict__ W2WoT,
             const float* __restrict__ s1, const float* __restrict__ Wo,
             const float* __restrict__ bo, float* __restrict__ spo,
             float* __restrict__ part) {
  __shared__ float red[8][8][64];   // spo reduce (16 KB)
  int blk = blockIdx.x;
  int tid = threadIdx.x;
  if (blk < 8) {            // ---- W2WoT = (W2@Wo)^T tile
    gemm64_core(WoT, W2b, W2WoT, blk * 64);
  } else if (blk < 16) {    // ---- spo[b][n] = bo[n] + sum_j s1[b][j]*Wo[j][n]
    int bb = blk - 8;                     // n in [bb*64, bb*64+64)
    int tn = tid & 63, tj = tid >> 6;     // 8 stripes of 64 j
    float a[8] = {0,0,0,0,0,0,0,0};
    for (int j = tj * 64; j < tj * 64 + 64; ++j) {
      float wv = Wo[(size_t)j * 512 + bb * 64 + tn];   // coalesced
#pragma unroll
      for (int b = 0; b < 8; ++b) a[b] += s1[b * 512 + j] * wv;
    }
#pragma unroll
    for (int b = 0; b < 8; ++b) red[tj][b][tn] = a[b];
    __syncthreads();
    if (tj == 0) {
#pragma unroll
      for (int b = 0; b < 8; ++b) {
        float s = 0.f;
#pragma unroll
        for (int k = 0; k < 8; ++k) s += red[k][b][tn];
        spo[b * 512 + bb * 64 + tn] = s + bo[bb * 64 + tn];
      }
    }
  } else {                  // ---- part: in-place EXCLUSIVE prefix over chunks
    int idx = (blk - 16) * 512 + tid;   // B*(D/4) = 1024 threads
    int d4 = idx & 127;
    int b  = idx >> 7;
    float* p = part + (size_t)b * NC * Dn + d4 * 4;
    float s[4] = {0, 0, 0, 0};
    for (int c0 = 0; c0 < NC; c0 += 8) {         // batch 8 loads in flight
      U4f v[8];
#pragma unroll
      for (int i = 0; i < 8; ++i) v[i].f4 = *(const float4*)(p + (size_t)(c0 + i) * Dn);
#pragma unroll
      for (int i = 0; i < 8; ++i) {
        U4f o;
#pragma unroll
        for (int j = 0; j < 4; ++j) { o.f[j] = s[j]; s[j] += v[i].f[j]; }
        *(float4*)(p + (size_t)(c0 + i) * Dn) = o.f4;
      }
    }
  }
}

// ===== dispatch 3: scan apply (running mean -> bf16 M), exclusive part =====
__global__ void k_scan_apply(const float* __restrict__ dec,
                             const float* __restrict__ part,
                             unsigned short* __restrict__ M) {
  int idx = blockIdx.x * 256 + threadIdx.x;   // B*NC*(D/4) = 131072 threads
  int d4 = idx & 127;
  int c  = (idx >> 7) & (NC - 1);
  int b  = idx >> 14;
  size_t rbase = (size_t)b * Tn + (size_t)c * CTm;
  U4f s; s.f4 = *(const float4*)(part + ((size_t)b * NC + c) * Dn + d4 * 4);
  int t0 = c * CTm;
  const float* dp = dec + rbase * Dn + d4 * 4;
  unsigned short* mp = M + rbase * Dn + d4 * 4;
#pragma unroll 4
  for (int i = 0; i < CTm; ++i) {
    U4f v; v.f4 = *(const float4*)(dp + (size_t)i * Dn);
    float inv = 1.0f / (float)(t0 + i + 1);
    U4s o;
#pragma unroll
    for (int j = 0; j < 4; ++j) { s.f[j] += v.f[j]; o.us[j] = f2b(s.f[j] * inv); }
    *(uint2*)(mp + (size_t)i * Dn) = o.u2;
  }
}

// ===== dispatch 4: fused H-GEMM -> H-in-LDS -> F-GEMM -> residual+LN ========
// 512 blocks x 1024 thr (16 waves: 4 M-bands of 16 rows x 4 N-bands of 128).
// BM=64 rows per block.  Phase 1: acc1[8] = M@Wh (counted-vmcnt dbuf K-loop).
// Then the ENTIRE 64x512 H tile = tanh(acc1+bh) is written to sH (64 KB, 16
// K-chunk sub-tiles in the exact phase-1 sA layout+swizzle) and acc1 DIES --
// this kills the R10/R11 spill (acc1+acc2 never simultaneously live; all
// register arrays statically indexed, rule #20).  Phase 2: acc2[8] = H@W2WoT,
// A-frags from sH, B dbuf-staged from L2 with counted vmcnt(2).
// Epilogue: fused residual+LayerNorm.  LDS 8+64+64+2 = 138 KB -> 1 block/CU.
__global__ __launch_bounds__(1024, 4)
void k_fused(const unsigned short* __restrict__ A,      // Mbuf
             const unsigned short* __restrict__ B1T,    // WhT
             const unsigned short* __restrict__ B2T,    // W2WoT
             const float* __restrict__ bh, const float* __restrict__ spo,
             const float* __restrict__ dec,
             const float* __restrict__ gamma, const float* __restrict__ beta,
             float* __restrict__ out) {
  __shared__ alignas(16) unsigned short sA[2][64 * 32];    // 8 KB
  __shared__ alignas(16) unsigned short sB[2][512 * 32];   // 64 KB
  __shared__ alignas(16) unsigned short sH[16][64 * 32];   // 64 KB
  __shared__ float lnS[64][4];
  __shared__ float lnQ[64][4];
  const int m0   = blockIdx.x * 64;
  const int tid  = threadIdx.x;
  const int lane = tid & 63;
  const int w    = tid >> 6;        // 0..15
  const int wr   = w >> 2;          // 0..3  (16-row band)
  const int wc   = w & 3;           // 0..3  (128-col band)
  const int rs   = lane & 15;
  const int quad = lane >> 4;

  const int co = (quad ^ ((rs >> 1) & 3)) * 8;   // swizzled read chunk (elems)

  auto STAGE1 = [&](int kt, int buf) {
    if (tid < 256) {                 // A: 64x32 = 256 16B chunks
      int r = tid >> 2, c = tid & 3;
      int kc = (c ^ ((r >> 1) & 3)) * 8;
      async16(A + (size_t)(m0 + r) * 512 + kt + kc, &sA[buf][tid * 8]);
    }
#pragma unroll
    for (int l = 0; l < 2; ++l) {    // B: 512x32 = 2048 chunks, 2/thread
      int ch = l * 1024 + tid;
      int r = ch >> 2, c = ch & 3;
      int kc = (c ^ ((r >> 1) & 3)) * 8;
      async16(B1T + (size_t)r * 512 + kt + kc, &sB[buf][ch * 8]);
    }
  };
  auto STAGE2 = [&](int kt, int buf) {
#pragma unroll
    for (int l = 0; l < 2; ++l) {
      int ch = l * 1024 + tid;
      int r = ch >> 2, c = ch & 3;
      int kc = (c ^ ((r >> 1) & 3)) * 8;
      async16(B2T + (size_t)r * 512 + kt + kc, &sB[buf][ch * 8]);
    }
  };

  // ---- phase 1: acc1 = M @ Wh ----
  floatx4 acc1[8];
#pragma unroll
  for (int j = 0; j < 8; ++j) acc1[j] = (floatx4){0.f, 0.f, 0.f, 0.f};

  STAGE1(0, 0);
  for (int t = 0; t < 15; ++t) {
    STAGE1((t + 1) * 32, (t + 1) & 1);
    // waves 0-3 issue 3 loads/step (A+2B), others 2; wait only current tile
    if (w < 4) asm volatile("s_waitcnt vmcnt(3)\n\ts_barrier" ::: "memory");
    else       asm volatile("s_waitcnt vmcnt(2)\n\ts_barrier" ::: "memory");
    {
      int buf = t & 1;
      __builtin_amdgcn_s_setprio(1);
      short8 af = *(const short8*)(&sA[buf][(wr * 16 + rs) * 32 + co]);
#pragma unroll
      for (int nj = 0; nj < 8; ++nj) {
        short8 bf = *(const short8*)(&sB[buf][(wc * 128 + nj * 16 + rs) * 32 + co]);
        acc1[nj] = __builtin_amdgcn_mfma_f32_16x16x32_bf16(af, bf, acc1[nj], 0, 0, 0);
      }
      __builtin_amdgcn_s_setprio(0);
    }
    asm volatile("s_barrier" ::: "memory");
  }
  asm volatile("s_waitcnt vmcnt(0)\n\ts_barrier" ::: "memory");
  {
    __builtin_amdgcn_s_setprio(1);
    short8 af = *(const short8*)(&sA[1][(wr * 16 + rs) * 32 + co]);
#pragma unroll
    for (int nj = 0; nj < 8; ++nj) {
      short8 bf = *(const short8*)(&sB[1][(wc * 128 + nj * 16 + rs) * 32 + co]);
      acc1[nj] = __builtin_amdgcn_mfma_f32_16x16x32_bf16(af, bf, acc1[nj], 0, 0, 0);
    }
    __builtin_amdgcn_s_setprio(0);
  }

  // ---- H = tanh(acc1 + bh) -> sH (sA layout per 32-col K-chunk); acc1 dies
  {
#pragma unroll
    for (int nj = 0; nj < 8; ++nj) {
      const float bb = bh[wc * 128 + nj * 16 + rs];
      const int kk = wc * 4 + (nj >> 1);           // K-chunk of this col group
      const int cbase = (nj & 1) * 2 + (rs >> 3);  // chunk idx within 32 cols
#pragma unroll
      for (int r = 0; r < 4; ++r) {
        const int row = wr * 16 + quad * 4 + r;
        const int sc = cbase ^ ((row >> 1) & 3);
        sH[kk][row * 32 + sc * 8 + (rs & 7)] = f2b(fast_tanh(acc1[nj][r] + bb));
      }
    }
  }
  // all waves past phase-1 reads of sB before restaging it (and H in flight)
  asm volatile("s_barrier" ::: "memory");

  // ---- phase 2: acc2 = H @ W2WoT ----
  floatx4 acc2[8];
#pragma unroll
  for (int j = 0; j < 8; ++j) acc2[j] = (floatx4){0.f, 0.f, 0.f, 0.f};

  STAGE2(0, 0);
  for (int kk = 0; kk < 16; ++kk) {
    if (kk < 15) {
      STAGE2((kk + 1) * 32, (kk + 1) & 1);
      // lgkmcnt(0) drains this wave's sH writes (kk=0) -> visible at barrier
      asm volatile("s_waitcnt vmcnt(2) lgkmcnt(0)\n\ts_barrier" ::: "memory");
    } else {
      asm volatile("s_waitcnt vmcnt(0) lgkmcnt(0)\n\ts_barrier" ::: "memory");
    }
    {
      int buf = kk & 1;
      __builtin_amdgcn_s_setprio(1);
      short8 af = *(const short8*)(&sH[kk][(wr * 16 + rs) * 32 + co]);
#pragma unroll
      for (int nj = 0; nj < 8; ++nj) {
        short8 bf = *(const short8*)(&sB[buf][(wc * 128 + nj * 16 + rs) * 32 + co]);
        acc2[nj] = __builtin_amdgcn_mfma_f32_16x16x32_bf16(af, bf, acc2[nj], 0, 0, 0);
      }
      __builtin_amdgcn_s_setprio(0);
    }
    asm volatile("s_barrier" ::: "memory");
  }

  // ---- epilogue: F = tanh(spo - acc2); x = F + dec; out = LN(x) ----
  const int bidx = m0 >> 12;              // batch (4096 rows each; 64 | 4096)
#pragma unroll
  for (int r = 0; r < 4; ++r) {
    const int lrow = wr * 16 + quad * 4 + r;
    const size_t rowg = (size_t)(m0 + lrow);
    float s = 0.f, sq = 0.f;
#pragma unroll
    for (int nj = 0; nj < 8; ++nj) {
      const int colg = wc * 128 + nj * 16 + rs;
      float sp = spo[bidx * Dn + colg];
      float dv = dec[rowg * 512 + colg];
      float xf = fast_tanh(sp - acc2[nj][r]) + dv;
      acc2[nj][r] = xf;
      s += xf; sq += xf * xf;
    }
#pragma unroll
    for (int o = 8; o > 0; o >>= 1) { s += __shfl_xor(s, o, 64); sq += __shfl_xor(sq, o, 64); }
    if (rs == 0) { lnS[lrow][wc] = s; lnQ[lrow][wc] = sq; }
  }
  __syncthreads();
#pragma unroll
  for (int r = 0; r < 4; ++r) {
    const int lrow = wr * 16 + quad * 4 + r;
    const size_t rowg = (size_t)(m0 + lrow);
    float s = 0.f, sq = 0.f;
#pragma unroll
    for (int k = 0; k < 4; ++k) { s += lnS[lrow][k]; sq += lnQ[lrow][k]; }
    float mu   = s * (1.0f / 512.0f);
    float var  = sq * (1.0f / 512.0f) - mu * mu;
    float rstd = rsqrtf(var + 1e-6f);
#pragma unroll
    for (int nj = 0; nj < 8; ++nj) {
      const int colg = wc * 128 + nj * 16 + rs;
      out[rowg * 512 + colg] = (acc2[nj][r] - mu) * rstd * gamma[colg] + beta[colg];
    }
  }
}

extern "C" void kernel_launch(void* const* d_in, const int* in_sizes, int n_in,
                              void* d_out, int out_size, void* d_ws, size_t ws_size,
                              hipStream_t stream) {
  (void)in_sizes; (void)n_in; (void)out_size; (void)ws_size;
  const float* summ = (const float*)d_in[0];
  const float* dec  = (const float*)d_in[1];
  const float* Wh   = (const float*)d_in[2];
  const float* bh   = (const float*)d_in[3];
  const float* W1   = (const float*)d_in[4];
  const float* W2   = (const float*)d_in[5];
  const float* Wo   = (const float*)d_in[6];
  const float* bo   = (const float*)d_in[7];
  const float* gam  = (const float*)d_in[8];
  const float* bet  = (const float*)d_in[9];
  float* out = (float*)d_out;

  char* ws = (char*)d_ws;
  unsigned short* Mbuf  = (unsigned short*)(ws);                 // 32 MB bf16 M
  float*          part  = (float*)(ws + 67108864);               // 2 MB fp32 chunk sums
  float*          spo   = (float*)(ws + 69206016);               // 16 KB
  unsigned short* WhT   = (unsigned short*)(ws + 69238784);      // 512 KB bf16
  unsigned short* WoT   = (unsigned short*)(ws + 69763072);      // 512 KB bf16
  unsigned short* W2b   = (unsigned short*)(ws + 70287360);      // 512 KB bf16
  unsigned short* W2WoT = (unsigned short*)(ws + 70811648);      // 512 KB bf16 (= (W2@Wo)^T)
  float*          s1    = (float*)(ws + 71335936);               // 16 KB fp32 (summ@W1)

  // 1: chunk sums + weight transposes/convert + s1 = summ@W1
  k_fuse1<<<680, 256, 0, stream>>>(dec, part, Wh, Wo, W2, W1, summ, WhT, WoT, W2b, s1);

  // 2: W2@Wo GEMM + spo = s1@Wo + bo + part exclusive-scan (parallel)
  k_fuse2<<<18, 512, 0, stream>>>(WoT, W2b, W2WoT, s1, Wo, bo, spo, part);

  // 3: causal running mean -> M (bf16), reading exclusive chunk-prefix
  k_scan_apply<<<512, 256, 0, stream>>>(dec, part, Mbuf);

  // 4: fused  H = tanh(M@Wh+bh)  ->  out = LN(tanh(spo - H@W2Wo) + dec)
  k_fused<<<512, 1024, 0, stream>>>(Mbuf, WhT, W2WoT, bh, spo, dec, gam, bet, out);
}